// Round 3
// baseline (1044.063 us; speedup 1.0000x reference)
//
#include <hip/hip_runtime.h>

// CostVolume2D: N=8, C=128, H=96, W=224, D=4 -> 81 channels.
// out[n, dy*9+dx, h, w] = mean_c f1[n,c,h,w] * f2[n,c,h+dy-4,w+dx-4] (0 if OOB)
//
// Round 7: occupancy fix. Rounds 4/5/6 all pinned at <=30% occupancy and
// 16-30% VALUBusy: the GRID (1008 blocks = 4 blocks/CU) was the cap, so
// each SIMD held ~3 waves of the SAME block -> every barrier/latency event
// convoyed the whole SIMD. Round 6 (barrier-free direct loads) regressed:
// per-lane sliding-window buffer_loads are 16-row gathers (L1-pipeline
// bound, VALU 16%). This round keeps the round-5 structure (shared LDS
// staging with contiguous loads, lgkm-only barriers, 2-deep prefetch) and
// halves TILE_W 32->16: grid 2016 blocks (8 blocks/CU, ~24 waves/CU).
// Blocks are mutually unsynchronized, so one block's barrier stall hides
// under another block's FMAs. Per-thread: 4 w-px x 9 dx = 36 accumulators.
//
// Block = 192 threads (3 waves), tile 16(w) x 16(h). Wave wb -> dy = 3*dyg+wb.

constexpr int Cn = 128;
constexpr int Hh = 96;
constexpr int Ww = 224;
constexpr int HW = Hh * Ww;       // 21504
constexpr int TILE_H = 16;
constexpr int TILE_W = 16;
constexpr int F2R = 18;           // TILE_H + 2 (3 dy span)
constexpr int F2C = 24;           // staged cols: TILE_W + 8
constexpr int F2S = 40;           // row stride floats: 10 quads, step 2 mod 8
constexpr int CT  = F2R * F2S;    // 720 floats per channel tile
constexpr int NG  = 6;            // float4 granules per staged row (24/4)
constexpr int SLOTS = F2R * NG;   // 108 staging slots

// Barrier with LDS-visibility drain ONLY. Global (vmcnt) loads stay in
// flight across the barrier; consumers get compiler-counted vmcnt(N).
__device__ __forceinline__ void sync_lgkm() {
    asm volatile("s_waitcnt lgkmcnt(0)" ::: "memory");
    __builtin_amdgcn_s_barrier();
    asm volatile("" ::: "memory");
}

__global__ __launch_bounds__(192, 6)
void costvol_kernel(const float* __restrict__ f1g, const float* __restrict__ f2g,
                    float* __restrict__ outg) {
    __shared__ float lds[2][CT];       // double buffer, 5760 B

    const int b    = blockIdx.x;
    const int xcd  = b & 7;            // consecutive block IDs round-robin XCDs
    const int j    = b >> 3;           // 0..251
    const int dyg  = j % 3;
    const int tp   = j / 3;            // 0..83
    const int tile = tp * 8 + xcd;     // same tile's 3 dy-groups -> same XCD
    const int wt   = tile % 14;
    const int ht   = (tile / 14) % 6;
    const int n    = tile / 84;

    const int h0 = ht * TILE_H;
    const int w0 = wt * TILE_W;
    const int d0 = dyg * 3;

    const int tid  = threadIdx.x;
    const int wb   = tid >> 6;         // wave id = dy offset in group
    const int lane = tid & 63;
    const int gx   = lane & 3;         // 4 w px: w = w0 + 4*gx + (0..3)
    const int gy   = lane >> 2;        // h row: h = h0 + gy

    // ---- staging: 108 float4 slots cover 18 rows x 6 granules ----
    const int  srow = tid / NG;
    const int  sg   = tid - srow * NG;
    const bool sAct = (tid < SLOTS);
    const int  yS   = h0 + d0 - 4 + srow;
    const int  xS   = w0 - 4 + 4 * sg;        // float4 granule, never straddles W
    const bool sVal = sAct && (yS >= 0) && (yS < Hh) && (xS >= 0) && (xS < Ww);
    const int  sOff = sVal ? (yS * Ww + xS) : 0;
    const int  sLds = srow * F2S + 4 * sg;

    const size_t nbase = (size_t)n * Cn * HW;
    const float* f1n = f1g + nbase;
    const float* f2n = f2g + nbase;

    const int hA    = h0 + gy;
    const int wA    = w0 + 4 * gx;
    const int f1off = hA * Ww + wA;
    const int ldsr  = (gy + wb) * F2S + 4 * gx;

    const float* f2s = f2n + sOff;     // staging source base (valid iff sVal)
    const float* f1b = f1n + f1off;

    const float* ldr0 = &lds[0][ldsr];
    const float* ldr1 = &lds[1][ldsr];
    float*       ldw0 = &lds[0][sLds];
    float*       ldw1 = &lds[1][sLds];

    float4 acc[9];
#pragma unroll
    for (int dx = 0; dx < 9; ++dx)
        acc[dx] = make_float4(0.f, 0.f, 0.f, 0.f);

    const float4 z4 = make_float4(0.f, 0.f, 0.f, 0.f);

    // ---- prologue: buffers for c=0,1; global pipeline primed 2 deep ----
    float4 stA = sVal ? *(const float4*)(f2s) : z4;            // f2(0)
    float4 stB = sVal ? *(const float4*)(f2s + HW) : z4;       // f2(1)
    float4 aA  = *(const float4*)(f1b);                        // f1(0)
    float4 aB  = *(const float4*)(f1b + HW);                   // f1(1)

    if (sAct) *(float4*)(ldw0) = stA;
    sync_lgkm();

    float4 qA0 = *(const float4*)(ldr0);                       // frags(0)
    float4 qA1 = *(const float4*)(ldr0 + 4);
    float4 qA2 = *(const float4*)(ldr0 + 8);
    if (sAct) *(float4*)(ldw1) = stB;                          // f2(1) -> buf1
    stA = sVal ? *(const float4*)(f2s + (size_t)2 * HW) : z4;  // f2(2)
    stB = sVal ? *(const float4*)(f2s + (size_t)3 * HW) : z4;  // f2(3)
    sync_lgkm();

    float4 qB0, qB1, qB2;

#pragma unroll 1
    for (int cc = 0; cc < Cn; cc += 2) {
        // ================= even channel c = cc =================
        {
            // frags(cc+1): buf1 was written before the LAST barrier -> ds_read
            // latency hides under this step's FMAs; drained at this barrier.
            qB0 = *(const float4*)(ldr1);
            qB1 = *(const float4*)(ldr1 + 4);
            qB2 = *(const float4*)(ldr1 + 8);
            if (sAct) *(float4*)(ldw0) = stA;                  // f2(cc+2)

            const float4 a0 = aA;                              // f1(cc)
            const int cf2 = (cc + 4 < Cn) ? (cc + 4) : (Cn - 2);
            const int cf1 = (cc + 2 < Cn) ? (cc + 2) : (Cn - 2);
            stA = sVal ? *(const float4*)(f2s + (size_t)cf2 * HW) : z4;
            aA  = *(const float4*)(f1b + (size_t)cf1 * HW);

            const float wv[12] = {qA0.x, qA0.y, qA0.z, qA0.w,
                                  qA1.x, qA1.y, qA1.z, qA1.w,
                                  qA2.x, qA2.y, qA2.z, qA2.w};
#pragma unroll
            for (int dx = 0; dx < 9; ++dx) {
                acc[dx].x += a0.x * wv[dx + 0];
                acc[dx].y += a0.y * wv[dx + 1];
                acc[dx].z += a0.z * wv[dx + 2];
                acc[dx].w += a0.w * wv[dx + 3];
            }
            sync_lgkm();
        }
        // ================= odd channel c = cc+1 =================
        {
            qA0 = *(const float4*)(ldr0);                      // frags(cc+2)
            qA1 = *(const float4*)(ldr0 + 4);
            qA2 = *(const float4*)(ldr0 + 8);
            if (sAct) *(float4*)(ldw1) = stB;                  // f2(cc+3)

            const float4 a0 = aB;                              // f1(cc+1)
            const int cf2 = (cc + 5 < Cn) ? (cc + 5) : (Cn - 1);
            const int cf1 = (cc + 3 < Cn) ? (cc + 3) : (Cn - 1);
            stB = sVal ? *(const float4*)(f2s + (size_t)cf2 * HW) : z4;
            aB  = *(const float4*)(f1b + (size_t)cf1 * HW);

            const float wv[12] = {qB0.x, qB0.y, qB0.z, qB0.w,
                                  qB1.x, qB1.y, qB1.z, qB1.w,
                                  qB2.x, qB2.y, qB2.z, qB2.w};
#pragma unroll
            for (int dx = 0; dx < 9; ++dx) {
                acc[dx].x += a0.x * wv[dx + 0];
                acc[dx].y += a0.y * wv[dx + 1];
                acc[dx].z += a0.z * wv[dx + 2];
                acc[dx].w += a0.w * wv[dx + 3];
            }
            sync_lgkm();
        }
    }

    // ---- writeout: 9 float4 per thread, coalesced 16B stores ----
    const float sc = 1.0f / 128.0f;
    const int dy = d0 + wb;
    float* ob = outg + (size_t)n * 81 * HW + (size_t)hA * Ww + wA;
#pragma unroll
    for (int dx = 0; dx < 9; ++dx) {
        const int k = dy * 9 + dx;
        float4 v = acc[dx];
        v.x *= sc; v.y *= sc; v.z *= sc; v.w *= sc;
        *(float4*)(ob + (size_t)k * HW) = v;
    }
}

extern "C" void kernel_launch(void* const* d_in, const int* in_sizes, int n_in,
                              void* d_out, int out_size, void* d_ws, size_t ws_size,
                              hipStream_t stream) {
    const float* f1 = (const float*)d_in[0];
    const float* f2 = (const float*)d_in[1];
    float* out = (float*)d_out;
    // grid: 672 tiles x 3 dy-groups, swizzled so a tile's 3 blocks share an XCD
    costvol_kernel<<<dim3(2016), dim3(192), 0, stream>>>(f1, f2, out);
}

// Round 4
// 324.236 us; speedup vs baseline: 3.2201x; 3.2201x over previous
//
#include <hip/hip_runtime.h>

// CostVolume2D: N=8, C=128, H=96, W=224, D=4 -> 81 channels.
// out[n, dy*9+dx, h, w] = mean_c f1[n,c,h,w] * f2[n,c,h+dy-4,w+dx-4] (0 if OOB)
//
// Round 8 = round 7 with the two self-inflicted regressions reverted.
// Round-7 post-mortem: __launch_bounds__(192,6) capped the allocator at 40
// VGPR -> acc[9] (36 VGPR) spilled to scratch (WRITE 57MB -> 1.95GB, FETCH
// -> 1.5GB, VALU 1.7%, 919us). Also F2S=40 made ds_read_b128 4-way bank
// aliased ((8gy+4gx)%32 repeats 4x in gy); F2S=44 is 2-way (free, m136).
// This round: launch_bounds(192,3) (round-5-proven; expect ~56-64 VGPR, no
// spill) and F2S=44. The occupancy theory finally gets a fair test:
// grid 2016 blocks (TILE_W=16) = ~8 mutually-unsynchronized blocks/CU,
// ~6 waves/SIMD from different blocks -> barrier convoys of one block hide
// under FMAs of others. Per-thread: 4 w-px x 9 dx = 36 accumulators.
//
// Block = 192 threads (3 waves), tile 16(w) x 16(h). Wave wb -> dy = 3*dyg+wb.

constexpr int Cn = 128;
constexpr int Hh = 96;
constexpr int Ww = 224;
constexpr int HW = Hh * Ww;       // 21504
constexpr int TILE_H = 16;
constexpr int TILE_W = 16;
constexpr int F2R = 18;           // TILE_H + 2 (3 dy span)
constexpr int F2S = 44;           // row stride: 44 -> 2-way read aliasing (free)
constexpr int CT  = F2R * F2S;    // 792 floats per channel tile
constexpr int NG  = 6;            // float4 granules per staged row (24/4)
constexpr int SLOTS = F2R * NG;   // 108 staging slots

// Barrier with LDS-visibility drain ONLY. Global (vmcnt) loads stay in
// flight across the barrier; consumers get compiler-counted vmcnt(N).
__device__ __forceinline__ void sync_lgkm() {
    asm volatile("s_waitcnt lgkmcnt(0)" ::: "memory");
    __builtin_amdgcn_s_barrier();
    asm volatile("" ::: "memory");
}

__global__ __launch_bounds__(192, 3)
void costvol_kernel(const float* __restrict__ f1g, const float* __restrict__ f2g,
                    float* __restrict__ outg) {
    __shared__ float lds[2][CT];       // double buffer, 6336 B

    const int b    = blockIdx.x;
    const int xcd  = b & 7;            // consecutive block IDs round-robin XCDs
    const int j    = b >> 3;           // 0..251
    const int dyg  = j % 3;
    const int tp   = j / 3;            // 0..83
    const int tile = tp * 8 + xcd;     // same tile's 3 dy-groups -> same XCD
    const int wt   = tile % 14;
    const int ht   = (tile / 14) % 6;
    const int n    = tile / 84;

    const int h0 = ht * TILE_H;
    const int w0 = wt * TILE_W;
    const int d0 = dyg * 3;

    const int tid  = threadIdx.x;
    const int wb   = tid >> 6;         // wave id = dy offset in group
    const int lane = tid & 63;
    const int gx   = lane & 3;         // 4 w px: w = w0 + 4*gx + (0..3)
    const int gy   = lane >> 2;        // h row: h = h0 + gy

    // ---- staging: 108 float4 slots cover 18 rows x 6 granules ----
    const int  srow = tid / NG;
    const int  sg   = tid - srow * NG;
    const bool sAct = (tid < SLOTS);
    const int  yS   = h0 + d0 - 4 + srow;
    const int  xS   = w0 - 4 + 4 * sg;        // float4 granule, never straddles W
    const bool sVal = sAct && (yS >= 0) && (yS < Hh) && (xS >= 0) && (xS < Ww);
    const int  sOff = sVal ? (yS * Ww + xS) : 0;
    const int  sLds = srow * F2S + 4 * sg;

    const size_t nbase = (size_t)n * Cn * HW;
    const float* f1n = f1g + nbase;
    const float* f2n = f2g + nbase;

    const int hA    = h0 + gy;
    const int wA    = w0 + 4 * gx;
    const int f1off = hA * Ww + wA;
    const int ldsr  = (gy + wb) * F2S + 4 * gx;

    const float* f2s = f2n + sOff;     // staging source base (valid iff sVal)
    const float* f1b = f1n + f1off;

    const float* ldr0 = &lds[0][ldsr];
    const float* ldr1 = &lds[1][ldsr];
    float*       ldw0 = &lds[0][sLds];
    float*       ldw1 = &lds[1][sLds];

    float4 acc[9];
#pragma unroll
    for (int dx = 0; dx < 9; ++dx)
        acc[dx] = make_float4(0.f, 0.f, 0.f, 0.f);

    const float4 z4 = make_float4(0.f, 0.f, 0.f, 0.f);

    // ---- prologue: buffers for c=0,1; global pipeline primed 2 deep ----
    float4 stA = sVal ? *(const float4*)(f2s) : z4;            // f2(0)
    float4 stB = sVal ? *(const float4*)(f2s + HW) : z4;       // f2(1)
    float4 aA  = *(const float4*)(f1b);                        // f1(0)
    float4 aB  = *(const float4*)(f1b + HW);                   // f1(1)

    if (sAct) *(float4*)(ldw0) = stA;
    sync_lgkm();

    float4 qA0 = *(const float4*)(ldr0);                       // frags(0)
    float4 qA1 = *(const float4*)(ldr0 + 4);
    float4 qA2 = *(const float4*)(ldr0 + 8);
    if (sAct) *(float4*)(ldw1) = stB;                          // f2(1) -> buf1
    stA = sVal ? *(const float4*)(f2s + (size_t)2 * HW) : z4;  // f2(2)
    stB = sVal ? *(const float4*)(f2s + (size_t)3 * HW) : z4;  // f2(3)
    sync_lgkm();

    float4 qB0, qB1, qB2;

#pragma unroll 1
    for (int cc = 0; cc < Cn; cc += 2) {
        // ================= even channel c = cc =================
        {
            // frags(cc+1): buf1 was written before the LAST barrier -> ds_read
            // latency hides under this step's FMAs; drained at this barrier.
            qB0 = *(const float4*)(ldr1);
            qB1 = *(const float4*)(ldr1 + 4);
            qB2 = *(const float4*)(ldr1 + 8);
            if (sAct) *(float4*)(ldw0) = stA;                  // f2(cc+2)

            const float4 a0 = aA;                              // f1(cc)
            const int cf2 = (cc + 4 < Cn) ? (cc + 4) : (Cn - 2);
            const int cf1 = (cc + 2 < Cn) ? (cc + 2) : (Cn - 2);
            stA = sVal ? *(const float4*)(f2s + (size_t)cf2 * HW) : z4;
            aA  = *(const float4*)(f1b + (size_t)cf1 * HW);

            const float wv[12] = {qA0.x, qA0.y, qA0.z, qA0.w,
                                  qA1.x, qA1.y, qA1.z, qA1.w,
                                  qA2.x, qA2.y, qA2.z, qA2.w};
#pragma unroll
            for (int dx = 0; dx < 9; ++dx) {
                acc[dx].x += a0.x * wv[dx + 0];
                acc[dx].y += a0.y * wv[dx + 1];
                acc[dx].z += a0.z * wv[dx + 2];
                acc[dx].w += a0.w * wv[dx + 3];
            }
            sync_lgkm();
        }
        // ================= odd channel c = cc+1 =================
        {
            qA0 = *(const float4*)(ldr0);                      // frags(cc+2)
            qA1 = *(const float4*)(ldr0 + 4);
            qA2 = *(const float4*)(ldr0 + 8);
            if (sAct) *(float4*)(ldw1) = stB;                  // f2(cc+3)

            const float4 a0 = aB;                              // f1(cc+1)
            const int cf2 = (cc + 5 < Cn) ? (cc + 5) : (Cn - 1);
            const int cf1 = (cc + 3 < Cn) ? (cc + 3) : (Cn - 1);
            stB = sVal ? *(const float4*)(f2s + (size_t)cf2 * HW) : z4;
            aB  = *(const float4*)(f1b + (size_t)cf1 * HW);

            const float wv[12] = {qB0.x, qB0.y, qB0.z, qB0.w,
                                  qB1.x, qB1.y, qB1.z, qB1.w,
                                  qB2.x, qB2.y, qB2.z, qB2.w};
#pragma unroll
            for (int dx = 0; dx < 9; ++dx) {
                acc[dx].x += a0.x * wv[dx + 0];
                acc[dx].y += a0.y * wv[dx + 1];
                acc[dx].z += a0.z * wv[dx + 2];
                acc[dx].w += a0.w * wv[dx + 3];
            }
            sync_lgkm();
        }
    }

    // ---- writeout: 9 float4 per thread, coalesced 16B stores ----
    const float sc = 1.0f / 128.0f;
    const int dy = d0 + wb;
    float* ob = outg + (size_t)n * 81 * HW + (size_t)hA * Ww + wA;
#pragma unroll
    for (int dx = 0; dx < 9; ++dx) {
        const int k = dy * 9 + dx;
        float4 v = acc[dx];
        v.x *= sc; v.y *= sc; v.z *= sc; v.w *= sc;
        *(float4*)(ob + (size_t)k * HW) = v;
    }
}

extern "C" void kernel_launch(void* const* d_in, const int* in_sizes, int n_in,
                              void* d_out, int out_size, void* d_ws, size_t ws_size,
                              hipStream_t stream) {
    const float* f1 = (const float*)d_in[0];
    const float* f2 = (const float*)d_in[1];
    float* out = (float*)d_out;
    // grid: 672 tiles x 3 dy-groups, swizzled so a tile's 3 blocks share an XCD
    costvol_kernel<<<dim3(2016), dim3(192), 0, stream>>>(f1, f2, out);
}